// Round 16
// baseline (49.207 us; speedup 1.0000x reference)
//
#include <hip/hip_runtime.h>
#include <hip/hip_bf16.h>

typedef unsigned short u16;
typedef unsigned int u32;
typedef unsigned long long u64;

typedef _Float16 vh8 __attribute__((ext_vector_type(8)));   // MFMA A/B frag
typedef _Float16 hv2 __attribute__((ext_vector_type(2)));
typedef __attribute__((ext_vector_type(16))) float vf16;    // MFMA acc

// ---------------- workspace layout (u32 units) ----------------
#define A1_OFF   0      // [3 kb][64 lane][4]  stage1 piece weights (K=48, hi-interleaved)
#define A2_OFF   1280   // [3 kb][64][4]       conv2 (kb0,kb1 used)
#define A3_OFF   2048   // [2 kb][64][4]       heads (kb0 used)
#define A4_OFF   2560   // [2 kb][64][4]       ob2 (kb0 used)
#define FH_OFF   3072   // [2 head][2 hi][16 c16][4 k][2 j] u32 of f16-pairs (512 u32)
#define FB_OFF   4096   // fbr[4], fbg[4] (f32)
#define FLAG_OFF 4104
#define T_OFF    4160   // [4 a][2 hi][4 rq][16 c16][4 rl] f32 (2048) = action+bias acc-init
#define BT_OFF   6208   // B2T[16] + B3T[32] + B4T[32] f32 bias acc-init tables

// ---------------- dtype helpers ----------------
__device__ __forceinline__ float bf2f(u16 h){ union{u32 u; float f;} v; v.u=((u32)h)<<16; return v.f; }
__device__ __forceinline__ u16 f2h(float f){ _Float16 h=(_Float16)f; return __builtin_bit_cast(u16,h); }
__device__ __forceinline__ float ldw(const void* p,int i,bool bf){ return bf? bf2f(((const u16*)p)[i]) : ((const float*)p)[i]; }

__device__ __forceinline__ bool detect_bf16(const void* w1){
  const u16* p=(const u16*)w1; bool ok=true;
  for(int k=0;k<64;++k){ float v=bf2f(p[k]); ok &= (fabsf(v)<=0.125f); }
  return ok;
}

// channel permutation: D-reg order -> B k-order (verified on HW in R2)
__device__ __constant__ int PI[32] = {0,1,2,3,8,9,10,11,4,5,6,7,12,13,14,15,
                                      16,17,18,19,24,25,26,27,20,21,22,23,28,29,30,31};

// ---------------- prep (parallelized across blocks, grid-stride) ----------------
__global__ __launch_bounds__(256) void dw_prep(
    const void* w1, const void* b1, const void* w2, const void* b2,
    const void* wo1, const void* bo1, const void* wo2, const void* bo2,
    const void* wr, const void* br, const void* fcr, const void* fbr,
    const void* wg, const void* bg, const void* fcg, const void* fbg,
    u32* wsu){
  const int gid = (int)(blockIdx.x*256 + threadIdx.x);
  const int gs  = (int)(gridDim.x*256);
  const bool bf = detect_bf16(w1);
  float* wsf = (float*)wsu;

  // A1 (pieces only): K = 16kb+8hi+2r+u; m=2r+u; tt=m>>2; q=m&3;
  // slot s = 2kb+tt; pos = 2s+hi; valid if s<5 && pos<=8.
  for (int t=gid; t<768; t+=gs){
    int kb=t>>8, l=(t>>2)&63, r=t&3, hi=l>>5, row=l&31;
    u32 w=0;
    for (int u=0;u<2;++u){
      int m=2*r+u, tt=m>>2, q=m&3, s=2*kb+tt;
      int pos = 2*s+hi;
      float v=0.f;
      if (s<5 && pos<=8) v = ldw(w1, row*72 + q*9 + pos, bf);
      w |= ((u32)f2h(v)) << (16*u);
    }
    wsu[A1_OFF+t]=w;
  }
  // T acc-init table: T[a][hi][rq][c16][rl] = b1[row] + sum valid taps w1[row][4+a][.]
  // row = rl + 8*rq + 4*hi  (C/D mapping of 32x32x16)
  for (int t=gid; t<2048; t+=gs){
    int a=t>>9, hi=(t>>8)&1, rq=(t>>6)&3, c16=(t>>2)&15, rl=t&3;
    int row = rl + 8*rq + 4*hi;
    int ci=c16>>2, cj=c16&3;
    float s0 = ldw(b1, row, bf);
    for (int dy=0; dy<3; ++dy)
      for (int dx=0; dx<3; ++dx){
        int ni=ci+dy-1, nj=cj+dx-1;
        if (ni>=0&&ni<4&&nj>=0&&nj<4)
          s0 += ldw(w1, row*72 + (4+a)*9 + dy*3+dx, bf);
      }
    wsf[T_OFF+t] = s0;
  }
  // A2: K<32: w2[row][PI[K]] (row<16)
  for (int t=gid; t<768; t+=gs){
    int kb=t>>8, l=(t>>2)&63, r=t&3, hi=l>>5, row=l&31;
    int K0=kb*16+hi*8+2*r; u32 w=0;
    for (int s=0;s<2;++s){
      int K=K0+s; float v=0.f;
      if (K<32){ if(row<16) v=ldw(w2, row*32+PI[K], bf); }
      w |= ((u32)f2h(v)) << (16*s);
    }
    wsu[A2_OFF+t]=w;
  }
  // A3: rows 0-15 Wob1, 16-23 Wr, 24-31 Wg; K<16 data (PI)
  for (int t=gid; t<512; t+=gs){
    int kb=t>>8, l=(t>>2)&63, r=t&3, hi=l>>5, row=l&31;
    int K0=kb*16+hi*8+2*r; u32 w=0;
    for (int s=0;s<2;++s){
      int K=K0+s; float v=0.f;
      if (K<16){
        int c=PI[K];
        v = (row<16)? ldw(wo1,row*16+c,bf) : (row<24)? ldw(wr,(row-16)*16+c,bf) : ldw(wg,(row-24)*16+c,bf);
      }
      w |= ((u32)f2h(v)) << (16*s);
    }
    wsu[A3_OFF+t]=w;
  }
  // A4: rows 0-7 Wob2; K<16 data
  for (int t=gid; t<512; t+=gs){
    int kb=t>>8, l=(t>>2)&63, r=t&3, hi=l>>5, row=l&31;
    int K0=kb*16+hi*8+2*r; u32 w=0;
    for (int s=0;s<2;++s){
      int K=K0+s; float v=0.f;
      if (row<8 && K<16) v=ldw(wo2, row*20+PI[K], bf);
      w |= ((u32)f2h(v)) << (16*s);
    }
    wsu[A4_OFF+t]=w;
  }
  // FH table (f16 pairs): idx = head*256 + hi*128 + c16*8 + k*2 + j
  for (int t=gid; t<512; t+=gs){
    int head=t>>8, r=t&255, hi=r>>7, c16=(r>>3)&15, k=(r>>1)&3, j=r&1;
    const void* f = head ? fcg : fcr;
    float v0 = ldw(f, k*128+(4*hi+2*j)*16+c16, bf);
    float v1 = ldw(f, k*128+(4*hi+2*j+1)*16+c16, bf);
    wsu[FH_OFF+t] = (u32)f2h(v0) | ((u32)f2h(v1)<<16);
  }
  for (int t=gid; t<8; t+=gs) wsf[FB_OFF+t] = ldw(t<4?fbr:fbg, t&3, bf);
  // bias acc-init tables
  for (int t=gid; t<16; t+=gs){
    int hi=t>>3, rq=(t>>2)&1, rl=t&3; int row=rl+8*rq+4*hi;
    wsf[BT_OFF+t] = ldw(b2,row,bf);
  }
  for (int t=gid; t<32; t+=gs){
    int hi=t>>4, rq=(t>>2)&3, rl=t&3; int row=rl+8*rq+4*hi;
    float v = (row<16)? ldw(bo1,row,bf) : (row<24)? ldw(br,row-16,bf) : ldw(bg,row-24,bf);
    wsf[BT_OFF+16+t]=v;
  }
  for (int t=gid; t<32; t+=gs){
    int p=t>>3, hi=(t>>2)&1, rl=t&3; int row=rl+4*hi;
    wsf[BT_OFF+48+t] = ldw(bo2,row,bf) + ldw(wo2,row*20+16+p,bf);
  }
  if (gid==0) wsu[FLAG_OFF] = bf ? 1u : 0u;
}

// ---------------- main kernel ----------------
// NBP[(hi<<4)|cell]: 5 fields x 6 bits; field s (pos=2s+hi): (inv<<5)|(nc<<1)
__host__ __device__ constexpr u32 nbpgen(int c, int hi){
  u32 v=0;
  for (int s=0;s<5;++s){
    int pos=2*s+hi; u32 f=32;
    if (pos<=8){
      int ni=c/4+pos/3-1, nj=c%4+pos%3-1;
      if (ni>=0&&ni<4&&nj>=0&&nj<4) f=(u32)((ni*4+nj)<<1);
    }
    v |= f << (6*s);
  }
  return v;
}
__device__ __constant__ u32 NBP[32] = {
  nbpgen(0,0),nbpgen(1,0),nbpgen(2,0),nbpgen(3,0),nbpgen(4,0),nbpgen(5,0),nbpgen(6,0),nbpgen(7,0),
  nbpgen(8,0),nbpgen(9,0),nbpgen(10,0),nbpgen(11,0),nbpgen(12,0),nbpgen(13,0),nbpgen(14,0),nbpgen(15,0),
  nbpgen(0,1),nbpgen(1,1),nbpgen(2,1),nbpgen(3,1),nbpgen(4,1),nbpgen(5,1),nbpgen(6,1),nbpgen(7,1),
  nbpgen(8,1),nbpgen(9,1),nbpgen(10,1),nbpgen(11,1),nbpgen(12,1),nbpgen(13,1),nbpgen(14,1),nbpgen(15,1)};

__device__ __forceinline__ vf16 mfma(int4 a, int4 b, vf16 c){
  union{int4 i; vh8 v;} ua, ub; ua.i=a; ub.i=b;
  return __builtin_amdgcn_mfma_f32_32x32x16_f16(ua.v, ub.v, c, 0, 0, 0);
}
__device__ __forceinline__ u32 pkh(float a, float b){
#if __has_builtin(__builtin_amdgcn_cvt_pkrtz)
  auto h = __builtin_amdgcn_cvt_pkrtz(a, b);
  return __builtin_bit_cast(u32, h);
#else
  return (u32)f2h(a) | ((u32)f2h(b)<<16);
#endif
}
__device__ __forceinline__ u32 pkmax0(u32 x){
  u32 d; asm("v_pk_max_f16 %0, %1, 0" : "=v"(d) : "v"(x)); return d;
}
__device__ __forceinline__ float dot2(u32 w, u32 x, float c){
#if __has_builtin(__builtin_amdgcn_fdot2)
  return __builtin_amdgcn_fdot2(__builtin_bit_cast(hv2,w), __builtin_bit_cast(hv2,x), c, false);
#else
  hv2 a=__builtin_bit_cast(hv2,w), b=__builtin_bit_cast(hv2,x);
  return c + (float)a[0]*(float)b[0] + (float)a[1]*(float)b[1];
#endif
}
__device__ __forceinline__ u32 pkbf(float a, float b){
  u16 lo=__builtin_bit_cast(u16,__float2bfloat16(a));
  u16 hi=__builtin_bit_cast(u16,__float2bfloat16(b));
  return (u32)lo | ((u32)hi<<16);
}
template<int CTRL> __device__ __forceinline__ float dppadd(float x){
  int y=__builtin_amdgcn_update_dpp(0,__builtin_bit_cast(int,x),CTRL,0xF,0xF,false);
  return x+__builtin_bit_cast(float,y);
}
template<int CTRL> __device__ __forceinline__ u32 dppor(u32 x){
  u32 y=(u32)__builtin_amdgcn_update_dpp(0,(int)x,CTRL,0xF,0xF,false);
  return x|y;
}
template<int CTRL> __device__ __forceinline__ float dppmov(float x){
  int y=__builtin_amdgcn_update_dpp(0,__builtin_bit_cast(int,x),CTRL,0xF,0xF,false);
  return __builtin_bit_cast(float,y);
}

__global__ __launch_bounds__(512) void dw_main(
    const int* __restrict__ ob, const int* __restrict__ ac,
    const u32* __restrict__ g, void* __restrict__ outp, int B){
  // LDS: used A-fragments + FH (6 KB) + bias tables (320 B); T read direct from L1
  __shared__ int4 sW4[384];
  __shared__ float4 sBT4[20];
  const int4* gA = (const int4*)g;
  const float4* gT = (const float4*)g;

  const int tid  = threadIdx.x;
  const int lane = tid & 63;
  const int hi   = lane >> 5;
  const int col  = lane & 31;
  const int c16  = col & 15;
  const int elem = col >> 4;
  const int wid  = tid >> 6;
  const int e = (int)(blockIdx.x<<4) + (wid<<1) + elem;
  const bool act = (e < B);
  const int eL = act ? e : 0;

  // ---- staging loads (issued first: ds_writes wait only on these) ----
  int4 w4 = make_int4(0,0,0,0); float4 bt4 = make_float4(0,0,0,0);
  const int srcw = tid + (tid<128 ? 320 : tid<192 ? 384 : tid<256 ? 448 : 512);
  if (tid < 384) w4 = gA[srcw];
  if (tid >= 384 && tid < 404) bt4 = gT[(BT_OFF>>2)+(tid-384)];

  // ---- prefetch own-cell board + action + A1 frags (latency hides under barrier) ----
  const u32 obc = (u32)ob[(size_t)eL*16 + c16];
  const int a = ac[eL];
  int4 A1f[3];
#pragma unroll
  for (int kb=0;kb<3;++kb) A1f[kb]=gA[(A1_OFF>>2)+kb*64+lane];

  if (tid < 384) sW4[tid] = w4;
  if (tid >= 384 && tid < 404) sBT4[tid-384] = bt4;
  __syncthreads();

  const bool obf = g[FLAG_OFF] != 0u;
  const float* gS = (const float*)g;
  const u32 nbp = NBP[(hi<<4)|c16];
  const vf16 zero = {0.f,0.f,0.f,0.f,0.f,0.f,0.f,0.f,0.f,0.f,0.f,0.f,0.f,0.f,0.f,0.f};
  const int xaddr = (lane^32)<<2;

  // ---- board pack: DPP row OR-all-reduce ----
  u32 pkv = obc << (c16<<1);
  pkv = dppor<0x121>(pkv);
  pkv = dppor<0x122>(pkv);
  pkv = dppor<0x124>(pkv);
  pkv = dppor<0x128>(pkv);

  // ---- stage-1 piece one-hot B-fragments (slots 0-4; slot 5 zero) ----
  int4 breg[3];
#pragma unroll
  for (int kb=0;kb<3;++kb){
    u32 w[4];
#pragma unroll
    for (int t=0;t<2;++t){
      const int s = kb*2+t;
      u32 w0=0, w1=0;
      if (s < 5){
        u32 v = (nbp >> (6*s)) & 63u;
        u32 np = (pkv >> (v & 31u)) & 3u;
        u32 src = (v < 32u) ? 0x3C00u : 0u;
        u64 oh = (u64)src << (np << 4);
        w0=(u32)oh; w1=(u32)(oh>>32);
      }
      w[2*t]=w0; w[2*t+1]=w1;
    }
    breg[kb]=make_int4(w[0],w[1],w[2],w[3]);
  }

  // ---- acc init = action+bias term from T table (direct, L1-hot) ----
  vf16 acc;
#pragma unroll
  for (int rq=0;rq<4;++rq){
    float4 q = gT[(T_OFF>>2) + (a*8 + hi*4 + rq)*16 + c16];
    acc[4*rq+0]=q.x; acc[4*rq+1]=q.y; acc[4*rq+2]=q.z; acc[4*rq+3]=q.w;
  }
#pragma unroll
  for (int kb=0;kb<3;++kb) acc = mfma(A1f[kb], breg[kb], acc);

  // ---- stage 2 (bias via acc init, 2 MFMAs) ----
  u32 zh[8];
#pragma unroll
  for (int i=0;i<8;++i) zh[i]=pkmax0(pkh(acc[2*i], acc[2*i+1]));
  vf16 acc2 = zero;
  {
    float4 q0 = sBT4[hi*2], q1 = sBT4[hi*2+1];
    acc2[0]=q0.x; acc2[1]=q0.y; acc2[2]=q0.z; acc2[3]=q0.w;
    acc2[4]=q1.x; acc2[5]=q1.y; acc2[6]=q1.z; acc2[7]=q1.w;
  }
  acc2 = mfma(sW4[lane], make_int4(zh[0],zh[1],zh[2],zh[3]), acc2);
  acc2 = mfma(sW4[64+lane], make_int4(zh[4],zh[5],zh[6],zh[7]), acc2);

  // ---- stage 3 (bias via acc init, 1 MFMA) ----
  u32 xh[4];
#pragma unroll
  for (int i=0;i<4;++i) xh[i]=pkmax0(pkh(acc2[2*i], acc2[2*i+1]));
  vf16 acc3;
#pragma unroll
  for (int rq=0;rq<4;++rq){
    float4 q = sBT4[4 + hi*4 + rq];
    acc3[4*rq+0]=q.x; acc3[4*rq+1]=q.y; acc3[4*rq+2]=q.z; acc3[4*rq+3]=q.w;
  }
  acc3 = mfma(sW4[128+lane], make_int4(xh[0],xh[1],xh[2],xh[3]), acc3);

  // ---- stage 4 (ob head; bias+piece via acc init, 1 MFMA) ----
  u32 nh[4];
#pragma unroll
  for (int i=0;i<4;++i) nh[i]=pkmax0(pkh(acc3[2*i], acc3[2*i+1]));
  const int p = (int)((pkv >> (c16<<1)) & 3u);
  vf16 acc4 = zero;
  {
    float4 q = sBT4[12 + p*2 + hi];
    acc4[0]=q.x; acc4[1]=q.y; acc4[2]=q.z; acc4[3]=q.w;
  }
  acc4 = mfma(sW4[192+lane], make_int4(nh[0],nh[1],nh[2],nh[3]), acc4);

  // ---- store next_ob (hi=0: loc, hi=1: scale) ----
  if (act){
    size_t bofs=(size_t)e*64 + c16*4;
    size_t off = hi ? ((size_t)B*64 + bofs) : bofs;
    if (obf){
      u16* o16=(u16*)outp;
      *(uint2*)(o16+off) = make_uint2(pkbf(acc4[0],acc4[1]), pkbf(acc4[2],acc4[3]));
    } else {
      float* of=(float*)outp;
      *(float4*)(of+off) = make_float4(acc4[0],acc4[1],acc4[2],acc4[3]);
    }
  }

  // ---- fc heads via f16 dot2 (tables from LDS); reduce-scatter ----
  u32 ra01 = pkmax0(pkh(acc3[8],  acc3[9]));
  u32 ra23 = pkmax0(pkh(acc3[10], acc3[11]));
  u32 ga01 = pkmax0(pkh(acc3[12], acc3[13]));
  u32 ga23 = pkmax0(pkh(acc3[14], acc3[15]));
  int4 tr0 = sW4[256 + hi*32 + c16*2];
  int4 tr1 = sW4[256 + hi*32 + c16*2 + 1];
  int4 tg0 = sW4[256 + 64 + hi*32 + c16*2];
  int4 tg1 = sW4[256 + 64 + hi*32 + c16*2 + 1];
  float rk[4], gk[4];
  rk[0] = dot2((u32)tr0.x, ra01, dot2((u32)tr0.y, ra23, 0.f));
  rk[1] = dot2((u32)tr0.z, ra01, dot2((u32)tr0.w, ra23, 0.f));
  rk[2] = dot2((u32)tr1.x, ra01, dot2((u32)tr1.y, ra23, 0.f));
  rk[3] = dot2((u32)tr1.z, ra01, dot2((u32)tr1.w, ra23, 0.f));
  gk[0] = dot2((u32)tg0.x, ga01, dot2((u32)tg0.y, ga23, 0.f));
  gk[1] = dot2((u32)tg0.z, ga01, dot2((u32)tg0.w, ga23, 0.f));
  gk[2] = dot2((u32)tg1.x, ga01, dot2((u32)tg1.y, ga23, 0.f));
  gk[3] = dot2((u32)tg1.z, ga01, dot2((u32)tg1.w, ga23, 0.f));

  const bool b0 = (c16&1), b1 = ((c16>>1)&1);
  float pr, pg;
  {
#pragma unroll
    for (int k=0;k<4;++k){ rk[k]=dppadd<0xB1>(rk[k]); gk[k]=dppadd<0xB1>(gk[k]); }
    float rp = b0 ? rk[2] : rk[0], rq = b0 ? rk[3] : rk[1];
    float gp = b0 ? gk[2] : gk[0], gq = b0 ? gk[3] : gk[1];
    rp=dppadd<0x4E>(rp); rq=dppadd<0x4E>(rq);
    gp=dppadd<0x4E>(gp); gq=dppadd<0x4E>(gq);
    pr = b1 ? rq : rp;
    pg = b1 ? gq : gp;
    pr=dppadd<0x124>(pr); pr=dppadd<0x128>(pr);
    pg=dppadd<0x124>(pg); pg=dppadd<0x128>(pg);
    int yr=__builtin_amdgcn_ds_bpermute(xaddr,__builtin_bit_cast(int,pr));
    int yg=__builtin_amdgcn_ds_bpermute(xaddr,__builtin_bit_cast(int,pg));
    pr += __builtin_bit_cast(float,yr);
    pg += __builtin_bit_cast(float,yg);
  }
  // pair exchange: lane c16=0 (k0) <- lane2 (k1); lane c16=1 (k2) <- lane3 (k3)
  float yr2 = dppmov<0x4E>(pr);
  float yg2 = dppmov<0x4E>(pg);
  if (act && hi==0 && c16<2){
    float fb0 = gS[FB_OFF + (c16<<1)];
    float fb1 = gS[FB_OFF + (c16<<1)+1];
    float fb2 = gS[FB_OFF + 4 + (c16<<1)];
    float fb3 = gS[FB_OFF + 4 + (c16<<1)+1];
    if (obf){
      u32* o32=(u32*)outp;
      o32[(size_t)B*64 + (size_t)c16*B + e]     = pkbf(pr+fb0, yr2+fb1);
      o32[(size_t)B*64 + (size_t)(2+c16)*B + e] = pkbf(pg+fb2, yg2+fb3);
    } else {
      float* of=(float*)outp;
      *(float2*)(of + (size_t)B*128 + (size_t)c16*2*B + (size_t)e*2)     = make_float2(pr+fb0, yr2+fb1);
      *(float2*)(of + (size_t)B*128 + (size_t)(2+c16)*2*B + (size_t)e*2) = make_float2(pg+fb2, yg2+fb3);
    }
  }
}

extern "C" void kernel_launch(void* const* d_in, const int* in_sizes, int n_in,
                              void* d_out, int out_size, void* d_ws, size_t ws_size,
                              hipStream_t stream) {
  const int* ob = (const int*)d_in[0];
  const int* ac = (const int*)d_in[1];
  u32* ws = (u32*)d_ws;
  const int B = in_sizes[1];

  hipLaunchKernelGGL(dw_prep, dim3(16), dim3(256), 0, stream,
                     d_in[2], d_in[3], d_in[4], d_in[5], d_in[6], d_in[7],
                     d_in[8], d_in[9], d_in[10], d_in[11], d_in[12], d_in[13],
                     d_in[14], d_in[15], d_in[16], d_in[17], ws);

  const int nb = (B + 15) / 16;
  hipLaunchKernelGGL(dw_main, dim3(nb), dim3(512), 0, stream, ob, ac, ws, d_out, B);
}

// Round 17
// 46.080 us; speedup vs baseline: 1.0679x; 1.0679x over previous
//
#include <hip/hip_runtime.h>
#include <hip/hip_bf16.h>

typedef unsigned short u16;
typedef unsigned int u32;
typedef unsigned long long u64;

typedef _Float16 vh8 __attribute__((ext_vector_type(8)));   // MFMA A/B frag
typedef _Float16 hv2 __attribute__((ext_vector_type(2)));
typedef __attribute__((ext_vector_type(16))) float vf16;    // MFMA acc

// ---------------- workspace layout (u32 units) ----------------
#define A1_OFF   0      // [3 kb][64 lane][4]  stage1 piece weights (K=48, hi-interleaved)
#define A2_OFF   1280   // [3 kb][64][4]       conv2 (kb0,kb1 used)
#define A3_OFF   2048   // [2 kb][64][4]       heads (kb0 used)
#define A4_OFF   2560   // [2 kb][64][4]       ob2 (kb0 used)
#define FH_OFF   3072   // [2 head][2 hi][16 c16][4 k][2 j] u32 of f16-pairs (512 u32)
#define FB_OFF   4096   // fbr[4], fbg[4] (f32)
#define FLAG_OFF 4104
#define T_OFF    4160   // [4 a][2 hi][4 rq][16 c16][4 rl] f32 (2048) = action+bias acc-init
#define BT_OFF   6208   // B2T[16] + B3T[32] + B4T[32] f32 bias acc-init tables

// ---------------- dtype helpers ----------------
__device__ __forceinline__ float bf2f(u16 h){ union{u32 u; float f;} v; v.u=((u32)h)<<16; return v.f; }
__device__ __forceinline__ u16 f2h(float f){ _Float16 h=(_Float16)f; return __builtin_bit_cast(u16,h); }
__device__ __forceinline__ float ldw(const void* p,int i,bool bf){ return bf? bf2f(((const u16*)p)[i]) : ((const float*)p)[i]; }

__device__ __forceinline__ bool detect_bf16(const void* w1){
  const u16* p=(const u16*)w1; bool ok=true;
  for(int k=0;k<64;++k){ float v=bf2f(p[k]); ok &= (fabsf(v)<=0.125f); }
  return ok;
}

// channel permutation: D-reg order -> B k-order (verified on HW in R2)
__device__ __constant__ int PI[32] = {0,1,2,3,8,9,10,11,4,5,6,7,12,13,14,15,
                                      16,17,18,19,24,25,26,27,20,21,22,23,28,29,30,31};

// ---------------- prep (parallelized across blocks, grid-stride) ----------------
__global__ __launch_bounds__(256) void dw_prep(
    const void* w1, const void* b1, const void* w2, const void* b2,
    const void* wo1, const void* bo1, const void* wo2, const void* bo2,
    const void* wr, const void* br, const void* fcr, const void* fbr,
    const void* wg, const void* bg, const void* fcg, const void* fbg,
    u32* wsu){
  const int gid = (int)(blockIdx.x*256 + threadIdx.x);
  const int gs  = (int)(gridDim.x*256);
  const bool bf = detect_bf16(w1);
  float* wsf = (float*)wsu;

  // A1 (pieces only): K = 16kb+8hi+2r+u; m=2r+u; tt=m>>2; q=m&3;
  // slot s = 2kb+tt; pos = 2s+hi; valid if s<5 && pos<=8.
  for (int t=gid; t<768; t+=gs){
    int kb=t>>8, l=(t>>2)&63, r=t&3, hi=l>>5, row=l&31;
    u32 w=0;
    for (int u=0;u<2;++u){
      int m=2*r+u, tt=m>>2, q=m&3, s=2*kb+tt;
      int pos = 2*s+hi;
      float v=0.f;
      if (s<5 && pos<=8) v = ldw(w1, row*72 + q*9 + pos, bf);
      w |= ((u32)f2h(v)) << (16*u);
    }
    wsu[A1_OFF+t]=w;
  }
  // T acc-init table: T[a][hi][rq][c16][rl] = b1[row] + sum valid taps w1[row][4+a][.]
  // row = rl + 8*rq + 4*hi  (C/D mapping of 32x32x16)
  for (int t=gid; t<2048; t+=gs){
    int a=t>>9, hi=(t>>8)&1, rq=(t>>6)&3, c16=(t>>2)&15, rl=t&3;
    int row = rl + 8*rq + 4*hi;
    int ci=c16>>2, cj=c16&3;
    float s0 = ldw(b1, row, bf);
    for (int dy=0; dy<3; ++dy)
      for (int dx=0; dx<3; ++dx){
        int ni=ci+dy-1, nj=cj+dx-1;
        if (ni>=0&&ni<4&&nj>=0&&nj<4)
          s0 += ldw(w1, row*72 + (4+a)*9 + dy*3+dx, bf);
      }
    wsf[T_OFF+t] = s0;
  }
  // A2: K<32: w2[row][PI[K]] (row<16)
  for (int t=gid; t<768; t+=gs){
    int kb=t>>8, l=(t>>2)&63, r=t&3, hi=l>>5, row=l&31;
    int K0=kb*16+hi*8+2*r; u32 w=0;
    for (int s=0;s<2;++s){
      int K=K0+s; float v=0.f;
      if (K<32){ if(row<16) v=ldw(w2, row*32+PI[K], bf); }
      w |= ((u32)f2h(v)) << (16*s);
    }
    wsu[A2_OFF+t]=w;
  }
  // A3: rows 0-15 Wob1, 16-23 Wr, 24-31 Wg; K<16 data (PI)
  for (int t=gid; t<512; t+=gs){
    int kb=t>>8, l=(t>>2)&63, r=t&3, hi=l>>5, row=l&31;
    int K0=kb*16+hi*8+2*r; u32 w=0;
    for (int s=0;s<2;++s){
      int K=K0+s; float v=0.f;
      if (K<16){
        int c=PI[K];
        v = (row<16)? ldw(wo1,row*16+c,bf) : (row<24)? ldw(wr,(row-16)*16+c,bf) : ldw(wg,(row-24)*16+c,bf);
      }
      w |= ((u32)f2h(v)) << (16*s);
    }
    wsu[A3_OFF+t]=w;
  }
  // A4: rows 0-7 Wob2; K<16 data
  for (int t=gid; t<512; t+=gs){
    int kb=t>>8, l=(t>>2)&63, r=t&3, hi=l>>5, row=l&31;
    int K0=kb*16+hi*8+2*r; u32 w=0;
    for (int s=0;s<2;++s){
      int K=K0+s; float v=0.f;
      if (row<8 && K<16) v=ldw(wo2, row*20+PI[K], bf);
      w |= ((u32)f2h(v)) << (16*s);
    }
    wsu[A4_OFF+t]=w;
  }
  // FH table (f16 pairs): idx = head*256 + hi*128 + c16*8 + k*2 + j
  for (int t=gid; t<512; t+=gs){
    int head=t>>8, r=t&255, hi=r>>7, c16=(r>>3)&15, k=(r>>1)&3, j=r&1;
    const void* f = head ? fcg : fcr;
    float v0 = ldw(f, k*128+(4*hi+2*j)*16+c16, bf);
    float v1 = ldw(f, k*128+(4*hi+2*j+1)*16+c16, bf);
    wsu[FH_OFF+t] = (u32)f2h(v0) | ((u32)f2h(v1)<<16);
  }
  for (int t=gid; t<8; t+=gs) wsf[FB_OFF+t] = ldw(t<4?fbr:fbg, t&3, bf);
  // bias acc-init tables
  for (int t=gid; t<16; t+=gs){
    int hi=t>>3, rq=(t>>2)&1, rl=t&3; int row=rl+8*rq+4*hi;
    wsf[BT_OFF+t] = ldw(b2,row,bf);
  }
  for (int t=gid; t<32; t+=gs){
    int hi=t>>4, rq=(t>>2)&3, rl=t&3; int row=rl+8*rq+4*hi;
    float v = (row<16)? ldw(bo1,row,bf) : (row<24)? ldw(br,row-16,bf) : ldw(bg,row-24,bf);
    wsf[BT_OFF+16+t]=v;
  }
  for (int t=gid; t<32; t+=gs){
    int p=t>>3, hi=(t>>2)&1, rl=t&3; int row=rl+4*hi;
    wsf[BT_OFF+48+t] = ldw(bo2,row,bf) + ldw(wo2,row*20+16+p,bf);
  }
  if (gid==0) wsu[FLAG_OFF] = bf ? 1u : 0u;
}

// ---------------- main kernel ----------------
// NBP[(hi<<4)|cell]: 5 fields x 6 bits; field s (pos=2s+hi): (inv<<5)|(nc<<1)
__host__ __device__ constexpr u32 nbpgen(int c, int hi){
  u32 v=0;
  for (int s=0;s<5;++s){
    int pos=2*s+hi; u32 f=32;
    if (pos<=8){
      int ni=c/4+pos/3-1, nj=c%4+pos%3-1;
      if (ni>=0&&ni<4&&nj>=0&&nj<4) f=(u32)((ni*4+nj)<<1);
    }
    v |= f << (6*s);
  }
  return v;
}
__device__ __constant__ u32 NBP[32] = {
  nbpgen(0,0),nbpgen(1,0),nbpgen(2,0),nbpgen(3,0),nbpgen(4,0),nbpgen(5,0),nbpgen(6,0),nbpgen(7,0),
  nbpgen(8,0),nbpgen(9,0),nbpgen(10,0),nbpgen(11,0),nbpgen(12,0),nbpgen(13,0),nbpgen(14,0),nbpgen(15,0),
  nbpgen(0,1),nbpgen(1,1),nbpgen(2,1),nbpgen(3,1),nbpgen(4,1),nbpgen(5,1),nbpgen(6,1),nbpgen(7,1),
  nbpgen(8,1),nbpgen(9,1),nbpgen(10,1),nbpgen(11,1),nbpgen(12,1),nbpgen(13,1),nbpgen(14,1),nbpgen(15,1)};

__device__ __forceinline__ vf16 mfma(int4 a, int4 b, vf16 c){
  union{int4 i; vh8 v;} ua, ub; ua.i=a; ub.i=b;
  return __builtin_amdgcn_mfma_f32_32x32x16_f16(ua.v, ub.v, c, 0, 0, 0);
}
__device__ __forceinline__ u32 pkh(float a, float b){
#if __has_builtin(__builtin_amdgcn_cvt_pkrtz)
  auto h = __builtin_amdgcn_cvt_pkrtz(a, b);
  return __builtin_bit_cast(u32, h);
#else
  return (u32)f2h(a) | ((u32)f2h(b)<<16);
#endif
}
__device__ __forceinline__ u32 pkmax0(u32 x){
  u32 d; asm("v_pk_max_f16 %0, %1, 0" : "=v"(d) : "v"(x)); return d;
}
__device__ __forceinline__ float dot2(u32 w, u32 x, float c){
#if __has_builtin(__builtin_amdgcn_fdot2)
  return __builtin_amdgcn_fdot2(__builtin_bit_cast(hv2,w), __builtin_bit_cast(hv2,x), c, false);
#else
  hv2 a=__builtin_bit_cast(hv2,w), b=__builtin_bit_cast(hv2,x);
  return c + (float)a[0]*(float)b[0] + (float)a[1]*(float)b[1];
#endif
}
__device__ __forceinline__ u32 pkbf(float a, float b){
  u16 lo=__builtin_bit_cast(u16,__float2bfloat16(a));
  u16 hi=__builtin_bit_cast(u16,__float2bfloat16(b));
  return (u32)lo | ((u32)hi<<16);
}
template<int CTRL> __device__ __forceinline__ float dppadd(float x){
  int y=__builtin_amdgcn_update_dpp(0,__builtin_bit_cast(int,x),CTRL,0xF,0xF,false);
  return x+__builtin_bit_cast(float,y);
}
template<int CTRL> __device__ __forceinline__ u32 dppor(u32 x){
  u32 y=(u32)__builtin_amdgcn_update_dpp(0,(int)x,CTRL,0xF,0xF,false);
  return x|y;
}
template<int CTRL> __device__ __forceinline__ float dppmov(float x){
  int y=__builtin_amdgcn_update_dpp(0,__builtin_bit_cast(int,x),CTRL,0xF,0xF,false);
  return __builtin_bit_cast(float,y);
}

__global__ __launch_bounds__(512) void dw_main(
    const int* __restrict__ ob, const int* __restrict__ ac,
    const u32* __restrict__ g, void* __restrict__ outp, int B){
  // LDS: used A-fragments + FH (6 KB) + bias tables (320 B) + T acc-init (8 KB)
  __shared__ int4 sW4[384];
  __shared__ float4 sBT4[20];
  __shared__ float4 sT4[512];
  const int4* gA = (const int4*)g;
  const float4* gT = (const float4*)g;

  const int tid  = threadIdx.x;
  const int lane = tid & 63;
  const int hi   = lane >> 5;
  const int col  = lane & 31;
  const int c16  = col & 15;
  const int elem = col >> 4;
  const int wid  = tid >> 6;
  const int e = (int)(blockIdx.x<<4) + (wid<<1) + elem;
  const bool act = (e < B);
  const int eL = act ? e : 0;

  // ---- staging loads (issued first: ds_writes wait only on these) ----
  int4 w4 = make_int4(0,0,0,0); float4 bt4 = make_float4(0,0,0,0);
  const int srcw = tid + (tid<128 ? 320 : tid<192 ? 384 : tid<256 ? 448 : 512);
  if (tid < 384) w4 = gA[srcw];
  float4 t4 = gT[(T_OFF>>2)+tid];
  if (tid >= 384 && tid < 404) bt4 = gT[(BT_OFF>>2)+(tid-384)];

  // ---- prefetch own-cell board + action + A1 frags (latency hides under barrier) ----
  const u32 obc = (u32)ob[(size_t)eL*16 + c16];
  const int a = ac[eL];
  int4 A1f[3];
#pragma unroll
  for (int kb=0;kb<3;++kb) A1f[kb]=gA[(A1_OFF>>2)+kb*64+lane];

  if (tid < 384) sW4[tid] = w4;
  sT4[tid] = t4;
  if (tid >= 384 && tid < 404) sBT4[tid-384] = bt4;
  __syncthreads();

  const bool obf = g[FLAG_OFF] != 0u;
  const float* gS = (const float*)g;
  const u32 nbp = NBP[(hi<<4)|c16];
  const vf16 zero = {0.f,0.f,0.f,0.f,0.f,0.f,0.f,0.f,0.f,0.f,0.f,0.f,0.f,0.f,0.f,0.f};
  const int xaddr = (lane^32)<<2;

  // ---- board pack: DPP row OR-all-reduce ----
  u32 pkv = obc << (c16<<1);
  pkv = dppor<0x121>(pkv);
  pkv = dppor<0x122>(pkv);
  pkv = dppor<0x124>(pkv);
  pkv = dppor<0x128>(pkv);

  // ---- stage-1 piece one-hot B-fragments (slots 0-4; slot 5 zero) ----
  int4 breg[3];
#pragma unroll
  for (int kb=0;kb<3;++kb){
    u32 w[4];
#pragma unroll
    for (int t=0;t<2;++t){
      const int s = kb*2+t;
      u32 w0=0, w1=0;
      if (s < 5){
        u32 v = (nbp >> (6*s)) & 63u;
        u32 np = (pkv >> (v & 31u)) & 3u;
        u32 src = (v < 32u) ? 0x3C00u : 0u;
        u64 oh = (u64)src << (np << 4);
        w0=(u32)oh; w1=(u32)(oh>>32);
      }
      w[2*t]=w0; w[2*t+1]=w1;
    }
    breg[kb]=make_int4(w[0],w[1],w[2],w[3]);
  }

  // ---- acc init = action+bias term from T table (LDS broadcast) ----
  vf16 acc;
#pragma unroll
  for (int rq=0;rq<4;++rq){
    float4 q = sT4[(a*8 + hi*4 + rq)*16 + c16];
    acc[4*rq+0]=q.x; acc[4*rq+1]=q.y; acc[4*rq+2]=q.z; acc[4*rq+3]=q.w;
  }
#pragma unroll
  for (int kb=0;kb<3;++kb) acc = mfma(A1f[kb], breg[kb], acc);

  // ---- stage 2 (bias via acc init, 2 MFMAs) ----
  u32 zh[8];
#pragma unroll
  for (int i=0;i<8;++i) zh[i]=pkmax0(pkh(acc[2*i], acc[2*i+1]));
  vf16 acc2 = zero;
  {
    float4 q0 = sBT4[hi*2], q1 = sBT4[hi*2+1];
    acc2[0]=q0.x; acc2[1]=q0.y; acc2[2]=q0.z; acc2[3]=q0.w;
    acc2[4]=q1.x; acc2[5]=q1.y; acc2[6]=q1.z; acc2[7]=q1.w;
  }
  acc2 = mfma(sW4[lane], make_int4(zh[0],zh[1],zh[2],zh[3]), acc2);
  acc2 = mfma(sW4[64+lane], make_int4(zh[4],zh[5],zh[6],zh[7]), acc2);

  // ---- stage 3 (bias via acc init, 1 MFMA) ----
  u32 xh[4];
#pragma unroll
  for (int i=0;i<4;++i) xh[i]=pkmax0(pkh(acc2[2*i], acc2[2*i+1]));
  vf16 acc3;
#pragma unroll
  for (int rq=0;rq<4;++rq){
    float4 q = sBT4[4 + hi*4 + rq];
    acc3[4*rq+0]=q.x; acc3[4*rq+1]=q.y; acc3[4*rq+2]=q.z; acc3[4*rq+3]=q.w;
  }
  acc3 = mfma(sW4[128+lane], make_int4(xh[0],xh[1],xh[2],xh[3]), acc3);

  // ---- stage 4 (ob head; bias+piece via acc init, 1 MFMA) ----
  u32 nh[4];
#pragma unroll
  for (int i=0;i<4;++i) nh[i]=pkmax0(pkh(acc3[2*i], acc3[2*i+1]));
  const int p = (int)((pkv >> (c16<<1)) & 3u);
  vf16 acc4 = zero;
  {
    float4 q = sBT4[12 + p*2 + hi];
    acc4[0]=q.x; acc4[1]=q.y; acc4[2]=q.z; acc4[3]=q.w;
  }
  acc4 = mfma(sW4[192+lane], make_int4(nh[0],nh[1],nh[2],nh[3]), acc4);

  // ---- store next_ob (hi=0: loc, hi=1: scale) ----
  if (act){
    size_t bofs=(size_t)e*64 + c16*4;
    size_t off = hi ? ((size_t)B*64 + bofs) : bofs;
    if (obf){
      u16* o16=(u16*)outp;
      *(uint2*)(o16+off) = make_uint2(pkbf(acc4[0],acc4[1]), pkbf(acc4[2],acc4[3]));
    } else {
      float* of=(float*)outp;
      *(float4*)(of+off) = make_float4(acc4[0],acc4[1],acc4[2],acc4[3]);
    }
  }

  // ---- fc heads via f16 dot2 (tables from LDS); reduce-scatter ----
  u32 ra01 = pkmax0(pkh(acc3[8],  acc3[9]));
  u32 ra23 = pkmax0(pkh(acc3[10], acc3[11]));
  u32 ga01 = pkmax0(pkh(acc3[12], acc3[13]));
  u32 ga23 = pkmax0(pkh(acc3[14], acc3[15]));
  int4 tr0 = sW4[256 + hi*32 + c16*2];
  int4 tr1 = sW4[256 + hi*32 + c16*2 + 1];
  int4 tg0 = sW4[256 + 64 + hi*32 + c16*2];
  int4 tg1 = sW4[256 + 64 + hi*32 + c16*2 + 1];
  float rk[4], gk[4];
  rk[0] = dot2((u32)tr0.x, ra01, dot2((u32)tr0.y, ra23, 0.f));
  rk[1] = dot2((u32)tr0.z, ra01, dot2((u32)tr0.w, ra23, 0.f));
  rk[2] = dot2((u32)tr1.x, ra01, dot2((u32)tr1.y, ra23, 0.f));
  rk[3] = dot2((u32)tr1.z, ra01, dot2((u32)tr1.w, ra23, 0.f));
  gk[0] = dot2((u32)tg0.x, ga01, dot2((u32)tg0.y, ga23, 0.f));
  gk[1] = dot2((u32)tg0.z, ga01, dot2((u32)tg0.w, ga23, 0.f));
  gk[2] = dot2((u32)tg1.x, ga01, dot2((u32)tg1.y, ga23, 0.f));
  gk[3] = dot2((u32)tg1.z, ga01, dot2((u32)tg1.w, ga23, 0.f));

  const bool b0 = (c16&1), b1 = ((c16>>1)&1);
  float pr, pg;
  {
#pragma unroll
    for (int k=0;k<4;++k){ rk[k]=dppadd<0xB1>(rk[k]); gk[k]=dppadd<0xB1>(gk[k]); }
    float rp = b0 ? rk[2] : rk[0], rq = b0 ? rk[3] : rk[1];
    float gp = b0 ? gk[2] : gk[0], gq = b0 ? gk[3] : gk[1];
    rp=dppadd<0x4E>(rp); rq=dppadd<0x4E>(rq);
    gp=dppadd<0x4E>(gp); gq=dppadd<0x4E>(gq);
    pr = b1 ? rq : rp;
    pg = b1 ? gq : gp;
    pr=dppadd<0x124>(pr); pr=dppadd<0x128>(pr);
    pg=dppadd<0x124>(pg); pg=dppadd<0x128>(pg);
    int yr=__builtin_amdgcn_ds_bpermute(xaddr,__builtin_bit_cast(int,pr));
    int yg=__builtin_amdgcn_ds_bpermute(xaddr,__builtin_bit_cast(int,pg));
    pr += __builtin_bit_cast(float,yr);
    pg += __builtin_bit_cast(float,yg);
  }
  // pair exchange: lane c16=0 (k0) <- lane2 (k1); lane c16=1 (k2) <- lane3 (k3)
  float yr2 = dppmov<0x4E>(pr);
  float yg2 = dppmov<0x4E>(pg);
  if (act && hi==0 && c16<2){
    float fb0 = gS[FB_OFF + (c16<<1)];
    float fb1 = gS[FB_OFF + (c16<<1)+1];
    float fb2 = gS[FB_OFF + 4 + (c16<<1)];
    float fb3 = gS[FB_OFF + 4 + (c16<<1)+1];
    if (obf){
      u32* o32=(u32*)outp;
      o32[(size_t)B*64 + (size_t)c16*B + e]     = pkbf(pr+fb0, yr2+fb1);
      o32[(size_t)B*64 + (size_t)(2+c16)*B + e] = pkbf(pg+fb2, yg2+fb3);
    } else {
      float* of=(float*)outp;
      *(float2*)(of + (size_t)B*128 + (size_t)c16*2*B + (size_t)e*2)     = make_float2(pr+fb0, yr2+fb1);
      *(float2*)(of + (size_t)B*128 + (size_t)(2+c16)*2*B + (size_t)e*2) = make_float2(pg+fb2, yg2+fb3);
    }
  }
}

extern "C" void kernel_launch(void* const* d_in, const int* in_sizes, int n_in,
                              void* d_out, int out_size, void* d_ws, size_t ws_size,
                              hipStream_t stream) {
  const int* ob = (const int*)d_in[0];
  const int* ac = (const int*)d_in[1];
  u32* ws = (u32*)d_ws;
  const int B = in_sizes[1];

  hipLaunchKernelGGL(dw_prep, dim3(16), dim3(256), 0, stream,
                     d_in[2], d_in[3], d_in[4], d_in[5], d_in[6], d_in[7],
                     d_in[8], d_in[9], d_in[10], d_in[11], d_in[12], d_in[13],
                     d_in[14], d_in[15], d_in[16], d_in[17], ws);

  const int nb = (B + 15) / 16;
  hipLaunchKernelGGL(dw_main, dim3(nb), dim3(512), 0, stream, ob, ac, ws, d_out, B);
}